// Round 9
// baseline (177.261 us; speedup 1.0000x reference)
//
#include <hip/hip_runtime.h>
#include <hip/hip_bf16.h>
#include <float.h>

// N=1024, M=1024, D=512, fp32 in/out.
// tanh(q+k) = 1 - 2/(1+exp2(CS*(q+k))), CS=2*log2(e), exp2 factorized:
// eq[n][d]=min(exp2(CS*qp),2^13)*c (c=2^-13 pre-scaled in proj),
// ekT[d][m]=min(exp2(CS*kp),2^13)^T.
// s[n,m] = -2*sum_d Ww[d]/(1+eq*ek) (row-const dropped; softmax shift-inv).
// R19: 8-term rational merge (1 rcp per 8 d via 3-level tree, c^8 scaling).
// R20-R25: score VALU floor ~33-36us; barrier-free reg-prefetch engine best.
// R26: fused combine into score (WRITE 33->4.4MB) but 1n/wave killed k-reuse.
// R27: 4n-reuse restored (load:eval 1:4), score 60.4us @ 2 waves/SIMD,
// VALUBusy 60% -> ~24us occupancy stall (wave count pinned at 2048 by tiling).
// R28: intra-block d-split x4. Block = 512 thr (8 waves) = (dh 0..3 d-quarter)
// x (mg 0..1 m-group): each wave same barrier-free engine on 128d x 128m x 4n
// (eval:load still 4:1, L2 traffic unchanged). dh>0 dump acc to LDS, one
// barrier, dh==0 sums 4 partials + fused epilogue. Grid (4,256) = 1024 blocks
// x 8 waves = 32 waves/CU (VGPR<=64, LDS 22KB). Pred: 60->~40us.
// ws: eq 2MB | ekT 2MB | vph/vpl 2MB | Ph/Pl 4MB | rsum 4KB.

#define NROWS 1024
#define DDIM  512
#define MDIM  1024

typedef __attribute__((ext_vector_type(8))) short s8v;    // 8 bf16, 4 VGPR
typedef __attribute__((ext_vector_type(4))) float f4v;
typedef __attribute__((ext_vector_type(2))) float v2f;

__device__ __forceinline__ float bf2f(ushort h) {
    return __uint_as_float(((unsigned)h) << 16);
}
__device__ __forceinline__ ushort2 f2bf2(float a, float b) {   // packed cvt
    __hip_bfloat162 t = __float22bfloat162_rn(float2{a, b});
    union { __hip_bfloat162 v; ushort2 u; } c; c.v = t;
    return c.u;
}
__device__ __forceinline__ void hl2(float a, float b, ushort2& h, ushort2& l) {
    h = f2bf2(a, b);
    l = f2bf2(a - bf2f(h.x), b - bf2f(h.y));
}

// ---------------- K1: fused projection GEMMs (MFMA bf16 hi/lo, A^T-B) --------
// z=0: eq[n][d]:  A=q,  B=Wq, bias col, exp2+clamp, *c. Block (0,0,0) zeroes rsum.
// z=1: ekT[d][m]: A=Wk, B=kk, bias row, exp2+clamp.
// z=2: vpT[d][m]: A=Wv, B=v,  bias row, bf16 h/l out.
__global__ __launch_bounds__(256) void proj_gemm(
    const float* __restrict__ q, const float* __restrict__ kk_,
    const float* __restrict__ v,
    const float* __restrict__ Wq, const float* __restrict__ bq,
    const float* __restrict__ Wk, const float* __restrict__ bk,
    const float* __restrict__ Wv, const float* __restrict__ bv,
    float* __restrict__ eq, float* __restrict__ ekT,
    ushort* __restrict__ vph, ushort* __restrict__ vpl,
    float* __restrict__ rsum, float CS)
{
    __shared__ ushort Ah[4096], Al[4096], Bh[4096], Bl[4096];   // 32 KB

    const float* A; const float* B; const float* bias;
    int biasRow;
    if (blockIdx.z == 0)      { A = q;   B = Wq;  bias = bq; biasRow = 0; }
    else if (blockIdx.z == 1) { A = Wk;  B = kk_; bias = bk; biasRow = 1; }
    else                      { A = Wv;  B = v;   bias = bv; biasRow = 1; }

    const int bi = (blockIdx.z == 0) ? blockIdx.x : blockIdx.y;
    const int bj = (blockIdx.z == 0) ? blockIdx.y : blockIdx.x;

    const int t    = threadIdx.x;
    const int lane = t & 63;
    const int w    = t >> 6;
    const int lm   = lane & 15;
    const int lq   = lane >> 4;
    const int i0   = bi * 64;
    const int j0   = bj * 64;
    const int mh   = (w >> 1) * 32;
    const int nh   = (w & 1) * 32;

    // zero rsum (1024 floats) for score's atomics
    if (blockIdx.z == 0 && blockIdx.x == 0 && blockIdx.y == 0) {
        float4 zz = {0.f, 0.f, 0.f, 0.f};
        *(float4*)&rsum[t * 4] = zz;
    }

    f4v acc[2][2] = {{{0.f,0.f,0.f,0.f},{0.f,0.f,0.f,0.f}},
                     {{0.f,0.f,0.f,0.f},{0.f,0.f,0.f,0.f}}};
    float4 pa[4], pb[4];

    const int sr = t >> 4, sc4 = t & 15;
#pragma unroll
    for (int p = 0; p < 4; ++p) {
        int r = sr + p * 16;
        pa[p] = *(const float4*)&A[(size_t)(i0 + r) * DDIM + sc4 * 4];
        pb[p] = *(const float4*)&B[(size_t)(j0 + r) * DDIM + sc4 * 4];
    }

    for (int kc = 0; kc < 8; ++kc) {
        __syncthreads();
#pragma unroll
        for (int p = 0; p < 4; ++p) {
            int r = sr + p * 16;
            int ad = r * 64 + (((sc4 >> 1) ^ (r & 7)) << 3) + (sc4 & 1) * 4;
            ushort2 h01, l01, h23, l23;
            hl2(pa[p].x, pa[p].y, h01, l01);
            hl2(pa[p].z, pa[p].w, h23, l23);
            ushort4 ha = {h01.x, h01.y, h23.x, h23.y};
            ushort4 la = {l01.x, l01.y, l23.x, l23.y};
            *(ushort4*)&Ah[ad] = ha;
            *(ushort4*)&Al[ad] = la;
            hl2(pb[p].x, pb[p].y, h01, l01);
            hl2(pb[p].z, pb[p].w, h23, l23);
            ushort4 hb = {h01.x, h01.y, h23.x, h23.y};
            ushort4 lb = {l01.x, l01.y, l23.x, l23.y};
            *(ushort4*)&Bh[ad] = hb;
            *(ushort4*)&Bl[ad] = lb;
        }
        __syncthreads();
        if (kc < 7) {
            const int k0 = (kc + 1) * 64;
#pragma unroll
            for (int p = 0; p < 4; ++p) {
                int r = sr + p * 16;
                pa[p] = *(const float4*)&A[(size_t)(i0 + r) * DDIM + k0 + sc4 * 4];
                pb[p] = *(const float4*)&B[(size_t)(j0 + r) * DDIM + k0 + sc4 * 4];
            }
        }
#pragma unroll
        for (int ks = 0; ks < 2; ++ks) {
            const int kb = ks * 4 + lq;
            s8v afh[2], afl[2], bfh[2], bfl[2];
#pragma unroll
            for (int g = 0; g < 2; ++g) {
                int ra = mh + g * 16 + lm;
                int rb = nh + g * 16 + lm;
                int aa = ra * 64 + ((kb ^ (ra & 7)) << 3);
                int ab = rb * 64 + ((kb ^ (rb & 7)) << 3);
                afh[g] = *(const s8v*)&Ah[aa];
                afl[g] = *(const s8v*)&Al[aa];
                bfh[g] = *(const s8v*)&Bh[ab];
                bfl[g] = *(const s8v*)&Bl[ab];
            }
#pragma unroll
            for (int mi = 0; mi < 2; ++mi)
#pragma unroll
                for (int ni = 0; ni < 2; ++ni) {
                    acc[mi][ni] = __builtin_amdgcn_mfma_f32_16x16x32_bf16(
                        afh[mi], bfh[ni], acc[mi][ni], 0, 0, 0);
                    acc[mi][ni] = __builtin_amdgcn_mfma_f32_16x16x32_bf16(
                        afh[mi], bfl[ni], acc[mi][ni], 0, 0, 0);
                    acc[mi][ni] = __builtin_amdgcn_mfma_f32_16x16x32_bf16(
                        afl[mi], bfh[ni], acc[mi][ni], 0, 0, 0);
                }
        }
    }

    const float CLAMP = 8192.0f;   // 2^13: scaled 8-term den < 2^104
    const float SCw   = 1.220703125e-4f;   // c = 2^-13 (pre-scale eq)
#pragma unroll
    for (int mi = 0; mi < 2; ++mi) {
#pragma unroll
        for (int ni = 0; ni < 2; ++ni) {
#pragma unroll
            for (int p = 0; p < 4; ++p) {
                int row = i0 + mh + mi * 16 + lq * 4 + p;
                int col = j0 + nh + ni * 16 + lm;
                float val = acc[mi][ni][p] + (biasRow ? bias[row] : bias[col]);
                if (blockIdx.z == 0) {
                    eq[(size_t)row * 512 + col] =
                        fminf(__builtin_amdgcn_exp2f(val * CS), CLAMP) * SCw;
                } else if (blockIdx.z == 1) {
                    ekT[(size_t)row * 1024 + col] =
                        fminf(__builtin_amdgcn_exp2f(val * CS), CLAMP);
                } else {
                    ushort2 h2 = f2bf2(val, val);
                    vph[(size_t)row * 1024 + col] = h2.x;
                    ushort2 l2 = f2bf2(val - bf2f(h2.x), 0.f);
                    vpl[(size_t)row * 1024 + col] = l2.x;
                }
            }
        }
    }
}

// ---------------- K2: score+softmax fused (d-split x4 in block) --------------
// P[n][m] = mask ? exp2(C2 * sum_{d=0..511} Ww[d]/(1+eq*ek)) : 0 -> bf16 h/l
// Block 512 thr = 8 waves: dh = w>>1 (d-quarter, 128 rows), mg = w&1
// (m-group, 128 m-cols). Each wave: barrier-free k-stream over its quarter,
// all 4 n from shared es (eval:load 4:1). dh>0 -> acc to LDS; barrier;
// dh==0 sums 4 partials + mask/exp2/bf16/rsum epilogue.
// Grid (4,256) = 1024 blocks = 32 waves/CU. LDS: es 8K + wws 2K + red 12K.

#define TREE8(K0,K1,K2,K3,K4,K5,K6,K7,DCQ)                                     \
    {                                                                          \
        float4 wgA = *(const float4*)&wws[(DCQ)];                              \
        float4 wgB = *(const float4*)&wws[(DCQ) + 4];                          \
        _Pragma("unroll")                                                      \
        for (int nn = 0; nn < 4; ++nn) {                                       \
            float4 egA = *(const float4*)&es[nn * 512 + (DCQ)];                \
            float4 egB = *(const float4*)&es[nn * 512 + (DCQ) + 4];            \
            v2f A0 = __builtin_elementwise_fma(K0, (v2f){egA.x, egA.x}, cc2);  \
            v2f A1 = __builtin_elementwise_fma(K1, (v2f){egA.y, egA.y}, cc2);  \
            v2f A2 = __builtin_elementwise_fma(K2, (v2f){egA.z, egA.z}, cc2);  \
            v2f A3 = __builtin_elementwise_fma(K3, (v2f){egA.w, egA.w}, cc2);  \
            v2f A4 = __builtin_elementwise_fma(K4, (v2f){egB.x, egB.x}, cc2);  \
            v2f A5 = __builtin_elementwise_fma(K5, (v2f){egB.y, egB.y}, cc2);  \
            v2f A6 = __builtin_elementwise_fma(K6, (v2f){egB.z, egB.z}, cc2);  \
            v2f A7 = __builtin_elementwise_fma(K7, (v2f){egB.w, egB.w}, cc2);  \
            v2f n01 = __builtin_elementwise_fma((v2f){wgA.y, wgA.y}, A0,       \
                                                (v2f){wgA.x, wgA.x} * A1);     \
            v2f d01 = A0 * A1;                                                 \
            v2f n23 = __builtin_elementwise_fma((v2f){wgA.w, wgA.w}, A2,       \
                                                (v2f){wgA.z, wgA.z} * A3);     \
            v2f d23 = A2 * A3;                                                 \
            v2f n45 = __builtin_elementwise_fma((v2f){wgB.y, wgB.y}, A4,       \
                                                (v2f){wgB.x, wgB.x} * A5);     \
            v2f d45 = A4 * A5;                                                 \
            v2f n67 = __builtin_elementwise_fma((v2f){wgB.w, wgB.w}, A6,       \
                                                (v2f){wgB.z, wgB.z} * A7);     \
            v2f d67 = A6 * A7;                                                 \
            v2f nA = __builtin_elementwise_fma(n01, d23, n23 * d01);           \
            v2f dA = d01 * d23;                                                \
            v2f nB = __builtin_elementwise_fma(n45, d67, n67 * d45);           \
            v2f dB = d45 * d67;                                                \
            v2f num = __builtin_elementwise_fma(nA, dB, nB * dA);              \
            v2f den = dA * dB;                                                 \
            v2f r = {__builtin_amdgcn_rcpf(den.x),                             \
                     __builtin_amdgcn_rcpf(den.y)};                            \
            acc[nn] = __builtin_elementwise_fma(num, r, acc[nn]);              \
        }                                                                      \
    }

__global__ __launch_bounds__(512) void score_kernel(const float* __restrict__ eq,
                                                    const float* __restrict__ ekT,
                                                    const float* __restrict__ Ww,
                                                    const int* __restrict__ mask,
                                                    ushort* __restrict__ Ph,
                                                    ushort* __restrict__ Pl,
                                                    float* __restrict__ rsum)
{
    __shared__ __align__(16) float es[4 * 512];        // 8 KB (pre-scaled eq)
    __shared__ __align__(16) float wws[512];           // 2 KB (scaled)
    __shared__ __align__(16) float red[3 * 2 * 64 * 8]; // 12 KB (d-partials)
    const int t    = threadIdx.x;
    const int lane = t & 63;
    const int w    = t >> 6;                 // 0..7
    const int mg   = w & 1;                  // m-group
    const int dh   = w >> 1;                 // d-quarter 0..3
    const int mw   = blockIdx.x * 256 + mg * 128;   // wave's m-base
    const int n0   = blockIdx.y * 4;
    const int db   = dh * 128;               // wave's d-base

    const float SC = 1.220703125e-4f;        // c = 2^-13

    // stage es: 4 rows x 512 floats = 512 float4-slots; 512 threads x 1
    {
        int nl = t >> 7, c4 = t & 127;
        *(float4*)&es[nl * 512 + c4 * 4] =
            *(const float4*)&eq[(size_t)(n0 + nl) * DDIM + c4 * 4];
    }
    wws[t] = Ww[t] * SC;                     // 512 threads, 512 elems

    // per-lane global k stream over d-quarter [db, db+128)
    const float* gk = ekT + (size_t)db * MDIM + mw + lane * 2;

    // prologue: rows 0..7 -> a
    v2f a0 = *(const v2f*)(gk + (size_t)0 * MDIM);
    v2f a1 = *(const v2f*)(gk + (size_t)1 * MDIM);
    v2f a2 = *(const v2f*)(gk + (size_t)2 * MDIM);
    v2f a3 = *(const v2f*)(gk + (size_t)3 * MDIM);
    v2f a4 = *(const v2f*)(gk + (size_t)4 * MDIM);
    v2f a5 = *(const v2f*)(gk + (size_t)5 * MDIM);
    v2f a6 = *(const v2f*)(gk + (size_t)6 * MDIM);
    v2f a7 = *(const v2f*)(gk + (size_t)7 * MDIM);

    __syncthreads();   // es/wws visible

    v2f acc[4] = {};
    const v2f cc2 = {1.220703125e-4f, 1.220703125e-4f};   // {c, c}

    for (int dc = 0; dc < 128; dc += 16) {
        const float* g8 = gk + (size_t)(dc + 8) * MDIM;
        v2f b0 = *(const v2f*)(g8 + (size_t)0 * MDIM);
        v2f b1 = *(const v2f*)(g8 + (size_t)1 * MDIM);
        v2f b2 = *(const v2f*)(g8 + (size_t)2 * MDIM);
        v2f b3 = *(const v2f*)(g8 + (size_t)3 * MDIM);
        v2f b4 = *(const v2f*)(g8 + (size_t)4 * MDIM);
        v2f b5 = *(const v2f*)(g8 + (size_t)5 * MDIM);
        v2f b6 = *(const v2f*)(g8 + (size_t)6 * MDIM);
        v2f b7 = *(const v2f*)(g8 + (size_t)7 * MDIM);

        TREE8(a0, a1, a2, a3, a4, a5, a6, a7, db + dc)

        if (dc + 16 < 128) {
            const float* g16 = gk + (size_t)(dc + 16) * MDIM;
            a0 = *(const v2f*)(g16 + (size_t)0 * MDIM);
            a1 = *(const v2f*)(g16 + (size_t)1 * MDIM);
            a2 = *(const v2f*)(g16 + (size_t)2 * MDIM);
            a3 = *(const v2f*)(g16 + (size_t)3 * MDIM);
            a4 = *(const v2f*)(g16 + (size_t)4 * MDIM);
            a5 = *(const v2f*)(g16 + (size_t)5 * MDIM);
            a6 = *(const v2f*)(g16 + (size_t)6 * MDIM);
            a7 = *(const v2f*)(g16 + (size_t)7 * MDIM);
        }

        TREE8(b0, b1, b2, b3, b4, b5, b6, b7, db + dc + 8)
    }

    // d-partial reduction: dh>0 waves dump, dh==0 sums + epilogue
    if (dh > 0) {
        float* rb = &red[(((dh - 1) * 2 + mg) * 64 + lane) * 8];
        *(v2f*)&rb[0] = acc[0];
        *(v2f*)&rb[2] = acc[1];
        *(v2f*)&rb[4] = acc[2];
        *(v2f*)&rb[6] = acc[3];
    }
    __syncthreads();
    if (dh == 0) {
#pragma unroll
        for (int i = 0; i < 3; ++i) {
            const float* rb = &red[((i * 2 + mg) * 64 + lane) * 8];
            acc[0] += *(const v2f*)&rb[0];
            acc[1] += *(const v2f*)&rb[2];
            acc[2] += *(const v2f*)&rb[4];
            acc[3] += *(const v2f*)&rb[6];
        }

        // fused softmax epilogue: mask + exp2 + bf16 h/l + row partials
        const float C2 = -2.8853900817779268f;   // -2*log2(e)
        const int m = mw + lane * 2;
        float rs[4];
#pragma unroll
        for (int nn = 0; nn < 4; ++nn) {
            int n = n0 + nn;
            int2 mk = *(const int2*)&mask[(size_t)n * MDIM + m];
            float p0 = mk.x ? __builtin_amdgcn_exp2f(acc[nn].x * C2) : 0.f;
            float p1 = mk.y ? __builtin_amdgcn_exp2f(acc[nn].y * C2) : 0.f;
            ushort2 h, l;
            hl2(p0, p1, h, l);
            *(ushort2*)&Ph[(size_t)n * MDIM + m] = h;
            *(ushort2*)&Pl[(size_t)n * MDIM + m] = l;
            rs[nn] = p0 + p1;
        }
#pragma unroll
        for (int off = 32; off; off >>= 1) {
            rs[0] += __shfl_xor(rs[0], off);
            rs[1] += __shfl_xor(rs[1], off);
            rs[2] += __shfl_xor(rs[2], off);
            rs[3] += __shfl_xor(rs[3], off);
        }
        if (lane == 0) {
#pragma unroll
            for (int nn = 0; nn < 4; ++nn)
                atomicAdd(&rsum[n0 + nn], rs[nn]);
        }
    }
}

// ---------------- K3: context MFMA (m-split x4 + LDS reduce) -----------------
// out[n][d] = (sum_m P[n][m]*vpT[d][m]) * rcp(rsum[n])
// grid (32,64) = 2048 blocks = 8/CU. Wave w sums m in [w*256,(w+1)*256);
// partials LDS-reduced by wave 0.
__global__ __launch_bounds__(256) void ctx_gemm(const ushort* __restrict__ Ph,
                                                const ushort* __restrict__ Pl,
                                                const ushort* __restrict__ vph,
                                                const ushort* __restrict__ vpl,
                                                const float* __restrict__ rsum,
                                                float* __restrict__ out)
{
    __shared__ __align__(16) float red[3 * 64 * 4];   // 3 KB
    const int t    = threadIdx.x;
    const int lane = t & 63;
    const int w    = t >> 6;
    const int lm   = lane & 15;
    const int lq   = lane >> 4;
    const int d0   = blockIdx.x * 16;
    const int n0   = blockIdx.y * 16;
    const int mb   = w * 256;

    const ushort* pAh = Ph  + (size_t)(n0 + lm) * MDIM + mb + lq * 8;
    const ushort* pAl = Pl  + (size_t)(n0 + lm) * MDIM + mb + lq * 8;
    const ushort* pBh = vph + (size_t)(d0 + lm) * MDIM + mb + lq * 8;
    const ushort* pBl = vpl + (size_t)(d0 + lm) * MDIM + mb + lq * 8;

    f4v acc = {0.f, 0.f, 0.f, 0.f};
#pragma unroll 4
    for (int m0 = 0; m0 < 256; m0 += 32) {
        s8v ah = *(const s8v*)(pAh + m0);
        s8v al = *(const s8v*)(pAl + m0);
        s8v bh = *(const s8v*)(pBh + m0);
        s8v bl = *(const s8v*)(pBl + m0);
        acc = __builtin_amdgcn_mfma_f32_16x16x32_bf16(ah, bh, acc, 0, 0, 0);
        acc = __builtin_amdgcn_mfma_f32_16x16x32_bf16(ah, bl, acc, 0, 0, 0);
        acc = __builtin_amdgcn_mfma_f32_16x16x32_bf16(al, bh, acc, 0, 0, 0);
    }

    if (w > 0) *(f4v*)&red[((w - 1) * 64 + lane) * 4] = acc;
    __syncthreads();
    if (w == 0) {
#pragma unroll
        for (int i = 0; i < 3; ++i)
            acc += *(const f4v*)&red[(i * 64 + lane) * 4];
#pragma unroll
        for (int p = 0; p < 4; ++p) {
            int nrow = n0 + lq * 4 + p;
            float inv = __builtin_amdgcn_rcpf(rsum[nrow]);
            out[(size_t)nrow * DDIM + d0 + lm] = acc[p] * inv;
        }
    }
}

extern "C" void kernel_launch(void* const* d_in, const int* in_sizes, int n_in,
                              void* d_out, int out_size, void* d_ws, size_t ws_size,
                              hipStream_t stream)
{
    const float* q    = (const float*)d_in[0];
    const float* k    = (const float*)d_in[1];
    const float* v    = (const float*)d_in[2];
    const int*   mask = (const int*)d_in[3];
    const float* Wq   = (const float*)d_in[4];
    const float* bq   = (const float*)d_in[5];
    const float* Wk   = (const float*)d_in[6];
    const float* bk   = (const float*)d_in[7];
    const float* Wv   = (const float*)d_in[8];
    const float* bv   = (const float*)d_in[9];
    const float* Ww   = (const float*)d_in[10];
    // d_in[11] (bw) cancels under softmax.

    float* ws    = (float*)d_ws;
    float* eq    = ws;                       // 512K floats [1024 n][512 d]
    float* ekT   = ws + 524288;              // 512K [512 d][1024 m]
    ushort* vph  = (ushort*)(ws + 1048576);  // 1M ushorts [512 d][1024 m]
    ushort* vpl  = (ushort*)(ws + 1310720);  // 1M ushorts
    ushort* Ph   = (ushort*)(ws + 1572864);  // 1M ushorts [1024 n][1024 m]
    ushort* Pl   = (ushort*)(ws + 2097152);  // 1M ushorts
    float* rsum  = ws + 2621440;             // 1K floats
    float* out   = (float*)d_out;

    const float CS = 2.8853900817779268f;    // 2*log2(e)

    proj_gemm<<<dim3(16, 8, 3), dim3(256), 0, stream>>>(q, k, v, Wq, bq, Wk, bk,
                                                        Wv, bv, eq, ekT,
                                                        vph, vpl, rsum, CS);
    score_kernel<<<dim3(4, 256), dim3(512), 0, stream>>>(eq, ekT, Ww, mask,
                                                         Ph, Pl, rsum);
    ctx_gemm<<<dim3(32, 64), dim3(256), 0, stream>>>(Ph, Pl, vph, vpl, rsum, out);
}

// Round 10
// 175.771 us; speedup vs baseline: 1.0085x; 1.0085x over previous
//
#include <hip/hip_runtime.h>
#include <hip/hip_bf16.h>
#include <float.h>

// N=1024, M=1024, D=512, fp32 in/out.
// tanh(q+k) = 1 - 2/(1+exp2(CS*(q+k))), CS=2*log2(e), exp2 factorized:
// eq[n][d]=min(exp2(CS*qp),2^13)*c (c=2^-13 pre-scaled in proj),
// ekT[d][m]=min(exp2(CS*kp),2^13)^T.
// s[n,m] = -2*sum_d Ww[d]/(1+eq*ek) (row-const dropped; softmax shift-inv).
// R19: 8-term rational merge (1 rcp per 8 d via 3-level tree, c^8 scaling).
// R20-R28: score converged at 54-60us across 6 structures (VALU floor 33-38us;
// R27 4n-reuse fused version kept). Residue total-score = 107-124us for 10
// rounds; combine removal = ~8us, ctx swap = ~0 -> residue is proj OR fixed
// overhead. proj was 384 blocks = 1.5/CU, 16 barriers/block, latency-bound.
// R29: proj rewrite, single variable: (a) 64x32 tile -> 768 blocks = 3/CU,
// 12 waves/CU; (b) LDS double-buffer -> 1 barrier/chunk (9/block): MFMA(cur)
// overlaps ds_write(next) + global prefetch(next+1). LDS 48KB/block.
// Score = R27 exact. ctx = R23 exact. Falsifier: total unchanged -> proj
// small -> residue is harness overhead -> floor.
// ws: eq 2MB | ekT 2MB | vph/vpl 2MB | Ph/Pl 4MB | rsum 4KB.

#define NROWS 1024
#define DDIM  512
#define MDIM  1024

typedef __attribute__((ext_vector_type(8))) short s8v;    // 8 bf16, 4 VGPR
typedef __attribute__((ext_vector_type(4))) float f4v;
typedef __attribute__((ext_vector_type(2))) float v2f;

__device__ __forceinline__ float bf2f(ushort h) {
    return __uint_as_float(((unsigned)h) << 16);
}
__device__ __forceinline__ ushort2 f2bf2(float a, float b) {   // packed cvt
    __hip_bfloat162 t = __float22bfloat162_rn(float2{a, b});
    union { __hip_bfloat162 v; ushort2 u; } c; c.v = t;
    return c.u;
}
__device__ __forceinline__ void hl2(float a, float b, ushort2& h, ushort2& l) {
    h = f2bf2(a, b);
    l = f2bf2(a - bf2f(h.x), b - bf2f(h.y));
}

// ---------------- K1: fused projection GEMMs (64x32 tile, dbuf, 1 bar/chunk) -
// z=0: eq[n][d]:  A=q,  B=Wq, bias col, exp2+clamp, *c. Block (0,z0) zeroes rsum.
// z=1: ekT[d][m]: A=Wk, B=kk, bias row, exp2+clamp.
// z=2: vpT[d][m]: A=Wv, B=v,  bias row, bf16 h/l out.
// 256 blocks per z (z0: 16i x 16j; z1/z2: 8i x 32j), 768 total = 3/CU.
// Per chunk (K=64): A-tile 64xK, B-tile 32xK staged hi/lo bf16, XOR-swizzled.
// Wave w: i-half (w>>1)*32, j-half (w&1)*16; 12 MFMA/chunk/wave.
__global__ __launch_bounds__(256) void proj_gemm(
    const float* __restrict__ q, const float* __restrict__ kk_,
    const float* __restrict__ v,
    const float* __restrict__ Wq, const float* __restrict__ bq,
    const float* __restrict__ Wk, const float* __restrict__ bk,
    const float* __restrict__ Wv, const float* __restrict__ bv,
    float* __restrict__ eq, float* __restrict__ ekT,
    ushort* __restrict__ vph, ushort* __restrict__ vpl,
    float* __restrict__ rsum, float CS)
{
    // dbuf: [2] x (Ah 4096 + Al 4096 + Bh 2048 + Bl 2048) ushorts = 48 KB
    __shared__ ushort Ah[2][4096], Al[2][4096], Bh[2][2048], Bl[2][2048];

    const float* A; const float* B; const float* bias;
    int biasRow;
    if (blockIdx.z == 0)      { A = q;   B = Wq;  bias = bq; biasRow = 0; }
    else if (blockIdx.z == 1) { A = Wk;  B = kk_; bias = bk; biasRow = 1; }
    else                      { A = Wv;  B = v;   bias = bv; biasRow = 1; }

    const int bx = blockIdx.x;
    const int bi = (blockIdx.z == 0) ? (bx >> 4) : (bx >> 5);
    const int bj = (blockIdx.z == 0) ? (bx & 15) : (bx & 31);

    const int t    = threadIdx.x;
    const int lane = t & 63;
    const int w    = t >> 6;
    const int lm   = lane & 15;
    const int lq   = lane >> 4;
    const int i0   = bi * 64;
    const int j0   = bj * 32;
    const int mh   = (w >> 1) * 32;
    const int nh   = (w & 1) * 16;

    if (blockIdx.z == 0 && bx == 0) {       // zero rsum for score's atomics
        float4 zz = {0.f, 0.f, 0.f, 0.f};
        *(float4*)&rsum[t * 4] = zz;
    }

    const int sr = t >> 4, sc4 = t & 15;    // A: rows sr+p*16 (p<4); B: p<2

    // ---- staging helpers (regs -> LDS buf) ----
    float4 pa[4], pb[2];

#define LOAD_CHUNK(KC)                                                         \
    {                                                                          \
        const int k0 = (KC) * 64;                                              \
        _Pragma("unroll")                                                      \
        for (int p = 0; p < 4; ++p)                                            \
            pa[p] = *(const float4*)&A[(size_t)(i0 + sr + p * 16) * DDIM       \
                                       + k0 + sc4 * 4];                        \
        _Pragma("unroll")                                                      \
        for (int p = 0; p < 2; ++p)                                            \
            pb[p] = *(const float4*)&B[(size_t)(j0 + sr + p * 16) * DDIM       \
                                       + k0 + sc4 * 4];                        \
    }

#define WRITE_CHUNK(BUF)                                                       \
    {                                                                          \
        _Pragma("unroll")                                                      \
        for (int p = 0; p < 4; ++p) {                                          \
            int r = sr + p * 16;                                               \
            int ad = r * 64 + (((sc4 >> 1) ^ (r & 7)) << 3) + (sc4 & 1) * 4;   \
            ushort2 h01, l01, h23, l23;                                        \
            hl2(pa[p].x, pa[p].y, h01, l01);                                   \
            hl2(pa[p].z, pa[p].w, h23, l23);                                   \
            ushort4 ha = {h01.x, h01.y, h23.x, h23.y};                         \
            ushort4 la = {l01.x, l01.y, l23.x, l23.y};                         \
            *(ushort4*)&Ah[BUF][ad] = ha;                                      \
            *(ushort4*)&Al[BUF][ad] = la;                                      \
        }                                                                      \
        _Pragma("unroll")                                                      \
        for (int p = 0; p < 2; ++p) {                                          \
            int r = sr + p * 16;                                               \
            int ad = r * 64 + (((sc4 >> 1) ^ (r & 7)) << 3) + (sc4 & 1) * 4;   \
            ushort2 h01, l01, h23, l23;                                        \
            hl2(pb[p].x, pb[p].y, h01, l01);                                   \
            hl2(pb[p].z, pb[p].w, h23, l23);                                   \
            ushort4 hb = {h01.x, h01.y, h23.x, h23.y};                         \
            ushort4 lb = {l01.x, l01.y, l23.x, l23.y};                         \
            *(ushort4*)&Bh[BUF][ad] = hb;                                      \
            *(ushort4*)&Bl[BUF][ad] = lb;                                      \
        }                                                                      \
    }

    f4v acc[2] = {{0.f,0.f,0.f,0.f},{0.f,0.f,0.f,0.f}};

    // prologue: chunk 0 -> buf0; prefetch chunk 1 into regs
    LOAD_CHUNK(0)
    WRITE_CHUNK(0)
    LOAD_CHUNK(1)
    __syncthreads();

    for (int kc = 0; kc < 8; ++kc) {
        const int buf = kc & 1;
        // MFMA from buf (compiler interleaves with writes/loads below)
#pragma unroll
        for (int ks = 0; ks < 2; ++ks) {
            const int kb = ks * 4 + lq;
            s8v afh[2], afl[2], bfh, bfl;
#pragma unroll
            for (int g = 0; g < 2; ++g) {
                int ra = mh + g * 16 + lm;
                int aa = ra * 64 + ((kb ^ (ra & 7)) << 3);
                afh[g] = *(const s8v*)&Ah[buf][aa];
                afl[g] = *(const s8v*)&Al[buf][aa];
            }
            {
                int rb = nh + lm;
                int ab = rb * 64 + ((kb ^ (rb & 7)) << 3);
                bfh = *(const s8v*)&Bh[buf][ab];
                bfl = *(const s8v*)&Bl[buf][ab];
            }
#pragma unroll
            for (int mi = 0; mi < 2; ++mi) {
                acc[mi] = __builtin_amdgcn_mfma_f32_16x16x32_bf16(
                    afh[mi], bfh, acc[mi], 0, 0, 0);
                acc[mi] = __builtin_amdgcn_mfma_f32_16x16x32_bf16(
                    afh[mi], bfl, acc[mi], 0, 0, 0);
                acc[mi] = __builtin_amdgcn_mfma_f32_16x16x32_bf16(
                    afl[mi], bfh, acc[mi], 0, 0, 0);
            }
        }
        // stage chunk kc+1 (held in regs) into the other buffer
        if (kc < 7) {
            WRITE_CHUNK(buf ^ 1)
        }
        // prefetch chunk kc+2 into regs
        if (kc < 6) {
            LOAD_CHUNK(kc + 2)
        }
        __syncthreads();
    }

    const float CLAMP = 8192.0f;   // 2^13: scaled 8-term den < 2^104
    const float SCw   = 1.220703125e-4f;   // c = 2^-13 (pre-scale eq)
#pragma unroll
    for (int mi = 0; mi < 2; ++mi) {
#pragma unroll
        for (int p = 0; p < 4; ++p) {
            int row = i0 + mh + mi * 16 + lq * 4 + p;
            int col = j0 + nh + lm;
            float val = acc[mi][p] + (biasRow ? bias[row] : bias[col]);
            if (blockIdx.z == 0) {
                eq[(size_t)row * 512 + col] =
                    fminf(__builtin_amdgcn_exp2f(val * CS), CLAMP) * SCw;
            } else if (blockIdx.z == 1) {
                ekT[(size_t)row * 1024 + col] =
                    fminf(__builtin_amdgcn_exp2f(val * CS), CLAMP);
            } else {
                ushort2 h2 = f2bf2(val, val);
                vph[(size_t)row * 1024 + col] = h2.x;
                ushort2 l2 = f2bf2(val - bf2f(h2.x), 0.f);
                vpl[(size_t)row * 1024 + col] = l2.x;
            }
        }
    }
#undef LOAD_CHUNK
#undef WRITE_CHUNK
}

// ---------------- K2: score+softmax fused (full-d, 4n-reuse, barrier-free) ---
// P[n][m] = mask ? exp2(C2 * sum_{d=0..511} Ww[d]/(1+eq*ek)) : 0 -> bf16 h/l
// rsum[n] += wave partial (shfl-reduced, 1 atomic per wave per n).
// Block 4n x 512m x 512d: waves split M (wave w owns 128 m-cols, lane 2m);
// EVERY wave computes all 4 n from the shared es -> each loaded k-row serves
// 4n x 2m (load:eval 2:1). Barrier-free k-stream, named-reg dbuf.
// Grid (2,256) = 512 blocks = 2/CU. LDS: es 8KB + wws 2KB = 10KB.

#define TREE8(K0,K1,K2,K3,K4,K5,K6,K7,DCQ)                                     \
    {                                                                          \
        float4 wgA = *(const float4*)&wws[(DCQ)];                              \
        float4 wgB = *(const float4*)&wws[(DCQ) + 4];                          \
        _Pragma("unroll")                                                      \
        for (int nn = 0; nn < 4; ++nn) {                                       \
            float4 egA = *(const float4*)&es[nn * 512 + (DCQ)];                \
            float4 egB = *(const float4*)&es[nn * 512 + (DCQ) + 4];            \
            v2f A0 = __builtin_elementwise_fma(K0, (v2f){egA.x, egA.x}, cc2);  \
            v2f A1 = __builtin_elementwise_fma(K1, (v2f){egA.y, egA.y}, cc2);  \
            v2f A2 = __builtin_elementwise_fma(K2, (v2f){egA.z, egA.z}, cc2);  \
            v2f A3 = __builtin_elementwise_fma(K3, (v2f){egA.w, egA.w}, cc2);  \
            v2f A4 = __builtin_elementwise_fma(K4, (v2f){egB.x, egB.x}, cc2);  \
            v2f A5 = __builtin_elementwise_fma(K5, (v2f){egB.y, egB.y}, cc2);  \
            v2f A6 = __builtin_elementwise_fma(K6, (v2f){egB.z, egB.z}, cc2);  \
            v2f A7 = __builtin_elementwise_fma(K7, (v2f){egB.w, egB.w}, cc2);  \
            v2f n01 = __builtin_elementwise_fma((v2f){wgA.y, wgA.y}, A0,       \
                                                (v2f){wgA.x, wgA.x} * A1);     \
            v2f d01 = A0 * A1;                                                 \
            v2f n23 = __builtin_elementwise_fma((v2f){wgA.w, wgA.w}, A2,       \
                                                (v2f){wgA.z, wgA.z} * A3);     \
            v2f d23 = A2 * A3;                                                 \
            v2f n45 = __builtin_elementwise_fma((v2f){wgB.y, wgB.y}, A4,       \
                                                (v2f){wgB.x, wgB.x} * A5);     \
            v2f d45 = A4 * A5;                                                 \
            v2f n67 = __builtin_elementwise_fma((v2f){wgB.w, wgB.w}, A6,       \
                                                (v2f){wgB.z, wgB.z} * A7);     \
            v2f d67 = A6 * A7;                                                 \
            v2f nA = __builtin_elementwise_fma(n01, d23, n23 * d01);           \
            v2f dA = d01 * d23;                                                \
            v2f nB = __builtin_elementwise_fma(n45, d67, n67 * d45);           \
            v2f dB = d45 * d67;                                                \
            v2f num = __builtin_elementwise_fma(nA, dB, nB * dA);              \
            v2f den = dA * dB;                                                 \
            v2f r = {__builtin_amdgcn_rcpf(den.x),                             \
                     __builtin_amdgcn_rcpf(den.y)};                            \
            acc[nn] = __builtin_elementwise_fma(num, r, acc[nn]);              \
        }                                                                      \
    }

__global__ __launch_bounds__(256) void score_kernel(const float* __restrict__ eq,
                                                    const float* __restrict__ ekT,
                                                    const float* __restrict__ Ww,
                                                    const int* __restrict__ mask,
                                                    ushort* __restrict__ Ph,
                                                    ushort* __restrict__ Pl,
                                                    float* __restrict__ rsum)
{
    __shared__ __align__(16) float es[4 * 512];      // 8 KB (pre-scaled eq)
    __shared__ __align__(16) float wws[512];         // 2 KB (scaled)
    const int t    = threadIdx.x;
    const int lane = t & 63;
    const int w    = t >> 6;
    const int mw   = blockIdx.x * 512 + w * 128;     // wave's m-base
    const int n0   = blockIdx.y * 4;

    const float SC = 1.220703125e-4f;        // c = 2^-13

#pragma unroll
    for (int p = 0; p < 2; ++p) {
        int idx = t + p * 256;
        int nl = idx >> 7, c4 = idx & 127;
        *(float4*)&es[nl * 512 + c4 * 4] =
            *(const float4*)&eq[(size_t)(n0 + nl) * DDIM + c4 * 4];
    }
    wws[t]       = Ww[t] * SC;
    wws[t + 256] = Ww[t + 256] * SC;

    const float* gk = ekT + mw + lane * 2;

    v2f a0 = *(const v2f*)(gk + (size_t)0 * MDIM);
    v2f a1 = *(const v2f*)(gk + (size_t)1 * MDIM);
    v2f a2 = *(const v2f*)(gk + (size_t)2 * MDIM);
    v2f a3 = *(const v2f*)(gk + (size_t)3 * MDIM);
    v2f a4 = *(const v2f*)(gk + (size_t)4 * MDIM);
    v2f a5 = *(const v2f*)(gk + (size_t)5 * MDIM);
    v2f a6 = *(const v2f*)(gk + (size_t)6 * MDIM);
    v2f a7 = *(const v2f*)(gk + (size_t)7 * MDIM);

    __syncthreads();   // es/wws visible (only barrier in the kernel)

    v2f acc[4] = {};
    const v2f cc2 = {1.220703125e-4f, 1.220703125e-4f};   // {c, c}

    for (int dc = 0; dc < 512; dc += 16) {
        const float* g8 = gk + (size_t)(dc + 8) * MDIM;
        v2f b0 = *(const v2f*)(g8 + (size_t)0 * MDIM);
        v2f b1 = *(const v2f*)(g8 + (size_t)1 * MDIM);
        v2f b2 = *(const v2f*)(g8 + (size_t)2 * MDIM);
        v2f b3 = *(const v2f*)(g8 + (size_t)3 * MDIM);
        v2f b4 = *(const v2f*)(g8 + (size_t)4 * MDIM);
        v2f b5 = *(const v2f*)(g8 + (size_t)5 * MDIM);
        v2f b6 = *(const v2f*)(g8 + (size_t)6 * MDIM);
        v2f b7 = *(const v2f*)(g8 + (size_t)7 * MDIM);

        TREE8(a0, a1, a2, a3, a4, a5, a6, a7, dc)

        if (dc + 16 < 512) {
            const float* g16 = gk + (size_t)(dc + 16) * MDIM;
            a0 = *(const v2f*)(g16 + (size_t)0 * MDIM);
            a1 = *(const v2f*)(g16 + (size_t)1 * MDIM);
            a2 = *(const v2f*)(g16 + (size_t)2 * MDIM);
            a3 = *(const v2f*)(g16 + (size_t)3 * MDIM);
            a4 = *(const v2f*)(g16 + (size_t)4 * MDIM);
            a5 = *(const v2f*)(g16 + (size_t)5 * MDIM);
            a6 = *(const v2f*)(g16 + (size_t)6 * MDIM);
            a7 = *(const v2f*)(g16 + (size_t)7 * MDIM);
        }

        TREE8(b0, b1, b2, b3, b4, b5, b6, b7, dc + 8)
    }

    // fused softmax epilogue: mask + exp2 + bf16 h/l + row partials
    const float C2 = -2.8853900817779268f;   // -2*log2(e)
    const int m = mw + lane * 2;
    float rs[4];
#pragma unroll
    for (int nn = 0; nn < 4; ++nn) {
        int n = n0 + nn;
        int2 mk = *(const int2*)&mask[(size_t)n * MDIM + m];
        float p0 = mk.x ? __builtin_amdgcn_exp2f(acc[nn].x * C2) : 0.f;
        float p1 = mk.y ? __builtin_amdgcn_exp2f(acc[nn].y * C2) : 0.f;
        ushort2 h, l;
        hl2(p0, p1, h, l);
        *(ushort2*)&Ph[(size_t)n * MDIM + m] = h;
        *(ushort2*)&Pl[(size_t)n * MDIM + m] = l;
        rs[nn] = p0 + p1;
    }
#pragma unroll
    for (int off = 32; off; off >>= 1) {
        rs[0] += __shfl_xor(rs[0], off);
        rs[1] += __shfl_xor(rs[1], off);
        rs[2] += __shfl_xor(rs[2], off);
        rs[3] += __shfl_xor(rs[3], off);
    }
    if (lane == 0) {
#pragma unroll
        for (int nn = 0; nn < 4; ++nn)
            atomicAdd(&rsum[n0 + nn], rs[nn]);
    }
}

// ---------------- K3: context MFMA (m-split x4 + LDS reduce) -----------------
// out[n][d] = (sum_m P[n][m]*vpT[d][m]) * rcp(rsum[n])
// grid (32,64) = 2048 blocks = 8/CU. Wave w sums m in [w*256,(w+1)*256);
// partials LDS-reduced by wave 0.
__global__ __launch_bounds__(256) void ctx_gemm(const ushort* __restrict__ Ph,
                                                const ushort* __restrict__ Pl,
                                                const ushort* __restrict__ vph,
                                                const ushort* __restrict__ vpl,
                                                const float* __restrict__ rsum,
                                                float* __restrict__ out)
{
    __shared__ __align__(16) float red[3 * 64 * 4];   // 3 KB
    const int t    = threadIdx.x;
    const int lane = t & 63;
    const int w    = t >> 6;
    const int lm   = lane & 15;
    const int lq   = lane >> 4;
    const int d0   = blockIdx.x * 16;
    const int n0   = blockIdx.y * 16;
    const int mb   = w * 256;

    const ushort* pAh = Ph  + (size_t)(n0 + lm) * MDIM + mb + lq * 8;
    const ushort* pAl = Pl  + (size_t)(n0 + lm) * MDIM + mb + lq * 8;
    const ushort* pBh = vph + (size_t)(d0 + lm) * MDIM + mb + lq * 8;
    const ushort* pBl = vpl + (size_t)(d0 + lm) * MDIM + mb + lq * 8;

    f4v acc = {0.f, 0.f, 0.f, 0.f};
#pragma unroll 4
    for (int m0 = 0; m0 < 256; m0 += 32) {
        s8v ah = *(const s8v*)(pAh + m0);
        s8v al = *(const s8v*)(pAl + m0);
        s8v bh = *(const s8v*)(pBh + m0);
        s8v bl = *(const s8v*)(pBl + m0);
        acc = __builtin_amdgcn_mfma_f32_16x16x32_bf16(ah, bh, acc, 0, 0, 0);
        acc = __builtin_amdgcn_mfma_f32_16x16x32_bf16(ah, bl, acc, 0, 0, 0);
        acc = __builtin_amdgcn_mfma_f32_16x16x32_bf16(al, bh, acc, 0, 0, 0);
    }

    if (w > 0) *(f4v*)&red[((w - 1) * 64 + lane) * 4] = acc;
    __syncthreads();
    if (w == 0) {
#pragma unroll
        for (int i = 0; i < 3; ++i)
            acc += *(const f4v*)&red[(i * 64 + lane) * 4];
#pragma unroll
        for (int p = 0; p < 4; ++p) {
            int nrow = n0 + lq * 4 + p;
            float inv = __builtin_amdgcn_rcpf(rsum[nrow]);
            out[(size_t)nrow * DDIM + d0 + lm] = acc[p] * inv;
        }
    }
}

extern "C" void kernel_launch(void* const* d_in, const int* in_sizes, int n_in,
                              void* d_out, int out_size, void* d_ws, size_t ws_size,
                              hipStream_t stream)
{
    const float* q    = (const float*)d_in[0];
    const float* k    = (const float*)d_in[1];
    const float* v    = (const float*)d_in[2];
    const int*   mask = (const int*)d_in[3];
    const float* Wq   = (const float*)d_in[4];
    const float* bq   = (const float*)d_in[5];
    const float* Wk   = (const float*)d_in[6];
    const float* bk   = (const float*)d_in[7];
    const float* Wv   = (const float*)d_in[8];
    const float* bv   = (const float*)d_in[9];
    const float* Ww   = (const float*)d_in[10];
    // d_in[11] (bw) cancels under softmax.

    float* ws    = (float*)d_ws;
    float* eq    = ws;                       // 512K floats [1024 n][512 d]
    float* ekT   = ws + 524288;              // 512K [512 d][1024 m]
    ushort* vph  = (ushort*)(ws + 1048576);  // 1M ushorts [512 d][1024 m]
    ushort* vpl  = (ushort*)(ws + 1310720);  // 1M ushorts
    ushort* Ph   = (ushort*)(ws + 1572864);  // 1M ushorts [1024 n][1024 m]
    ushort* Pl   = (ushort*)(ws + 2097152);  // 1M ushorts
    float* rsum  = ws + 2621440;             // 1K floats
    float* out   = (float*)d_out;

    const float CS = 2.8853900817779268f;    // 2*log2(e)

    proj_gemm<<<dim3(256, 1, 3), dim3(256), 0, stream>>>(q, k, v, Wq, bq, Wk, bk,
                                                         Wv, bv, eq, ekT,
                                                         vph, vpl, rsum, CS);
    score_kernel<<<dim3(2, 256), dim3(256), 0, stream>>>(eq, ekT, Ww, mask,
                                                         Ph, Pl, rsum);
    ctx_gemm<<<dim3(32, 64), dim3(256), 0, stream>>>(Ph, Pl, vph, vpl, rsum, out);
}

// Round 11
// 172.925 us; speedup vs baseline: 1.0251x; 1.0165x over previous
//
#include <hip/hip_runtime.h>
#include <hip/hip_bf16.h>
#include <float.h>

// N=1024, M=1024, D=512, fp32 in/out.
// tanh(q+k) = 1 - 2/(1+exp2(CS*(q+k))), CS=2*log2(e), exp2 factorized:
// eq[n][d]=min(exp2(CS*qp),2^13)*c (c=2^-13 pre-scaled in proj),
// ekT[d][m]=min(exp2(CS*kp),2^13)^T.
// s[n,m] = -2*sum_d Ww[d]/(1+eq*ek) (row-const dropped; softmax shift-inv).
// R19: 8-term rational merge (1 rcp per 8 d via 3-level tree, c^8 scaling).
// R20-R28: score VALU floor ~36us; barrier-free reg-prefetch engine best;
// fused softmax epilogue (R26) keeps WRITE at 4.4MB.
// R29: proj rewrite NEUTRAL (175.8 vs 176.1) -> proj is small (also bounded
// <56us by R25's top-5). Residue ~114us ~= harness overhead (~17 dispatches/
// iter: reset memsets + 3 kernels) + proj/ctx (~15us each, physics).
// R30: score stall-gap attack: 2-way d-split, conflict-free reduction.
// Block 512thr = 8 waves = dh(2 x 256d) x mg(4 x 128m), all 4n shared.
// Same engine per wave (k-reuse + L2 traffic unchanged); dh=1 dumps acc to
// red[mg][comp][lane] (4B lane stride, 0 conflicts; R28's 32B stride caused
// 147K conflicts), 1 barrier, dh=0 adds + fused epilogue. 16 waves/CU
// (2x R27). Pred: score 61->~50, total ->~165.
// ws: eq 2MB | ekT 2MB | vph/vpl 2MB | Ph/Pl 4MB | rsum 4KB.

#define NROWS 1024
#define DDIM  512
#define MDIM  1024

typedef __attribute__((ext_vector_type(8))) short s8v;    // 8 bf16, 4 VGPR
typedef __attribute__((ext_vector_type(4))) float f4v;
typedef __attribute__((ext_vector_type(2))) float v2f;

__device__ __forceinline__ float bf2f(ushort h) {
    return __uint_as_float(((unsigned)h) << 16);
}
__device__ __forceinline__ ushort2 f2bf2(float a, float b) {   // packed cvt
    __hip_bfloat162 t = __float22bfloat162_rn(float2{a, b});
    union { __hip_bfloat162 v; ushort2 u; } c; c.v = t;
    return c.u;
}
__device__ __forceinline__ void hl2(float a, float b, ushort2& h, ushort2& l) {
    h = f2bf2(a, b);
    l = f2bf2(a - bf2f(h.x), b - bf2f(h.y));
}

// ---------------- K1: fused projection GEMMs (64x32 tile, dbuf, 1 bar/chunk) -
// z=0: eq[n][d]:  A=q,  B=Wq, bias col, exp2+clamp, *c. Block (0,z0) zeroes rsum.
// z=1: ekT[d][m]: A=Wk, B=kk, bias row, exp2+clamp.
// z=2: vpT[d][m]: A=Wv, B=v,  bias row, bf16 h/l out.
__global__ __launch_bounds__(256) void proj_gemm(
    const float* __restrict__ q, const float* __restrict__ kk_,
    const float* __restrict__ v,
    const float* __restrict__ Wq, const float* __restrict__ bq,
    const float* __restrict__ Wk, const float* __restrict__ bk,
    const float* __restrict__ Wv, const float* __restrict__ bv,
    float* __restrict__ eq, float* __restrict__ ekT,
    ushort* __restrict__ vph, ushort* __restrict__ vpl,
    float* __restrict__ rsum, float CS)
{
    __shared__ ushort Ah[2][4096], Al[2][4096], Bh[2][2048], Bl[2][2048];

    const float* A; const float* B; const float* bias;
    int biasRow;
    if (blockIdx.z == 0)      { A = q;   B = Wq;  bias = bq; biasRow = 0; }
    else if (blockIdx.z == 1) { A = Wk;  B = kk_; bias = bk; biasRow = 1; }
    else                      { A = Wv;  B = v;   bias = bv; biasRow = 1; }

    const int bx = blockIdx.x;
    const int bi = (blockIdx.z == 0) ? (bx >> 4) : (bx >> 5);
    const int bj = (blockIdx.z == 0) ? (bx & 15) : (bx & 31);

    const int t    = threadIdx.x;
    const int lane = t & 63;
    const int w    = t >> 6;
    const int lm   = lane & 15;
    const int lq   = lane >> 4;
    const int i0   = bi * 64;
    const int j0   = bj * 32;
    const int mh   = (w >> 1) * 32;
    const int nh   = (w & 1) * 16;

    if (blockIdx.z == 0 && bx == 0) {       // zero rsum for score's atomics
        float4 zz = {0.f, 0.f, 0.f, 0.f};
        *(float4*)&rsum[t * 4] = zz;
    }

    const int sr = t >> 4, sc4 = t & 15;

    float4 pa[4], pb[2];

#define LOAD_CHUNK(KC)                                                         \
    {                                                                          \
        const int k0 = (KC) * 64;                                              \
        _Pragma("unroll")                                                      \
        for (int p = 0; p < 4; ++p)                                            \
            pa[p] = *(const float4*)&A[(size_t)(i0 + sr + p * 16) * DDIM       \
                                       + k0 + sc4 * 4];                        \
        _Pragma("unroll")                                                      \
        for (int p = 0; p < 2; ++p)                                            \
            pb[p] = *(const float4*)&B[(size_t)(j0 + sr + p * 16) * DDIM       \
                                       + k0 + sc4 * 4];                        \
    }

#define WRITE_CHUNK(BUF)                                                       \
    {                                                                          \
        _Pragma("unroll")                                                      \
        for (int p = 0; p < 4; ++p) {                                          \
            int r = sr + p * 16;                                               \
            int ad = r * 64 + (((sc4 >> 1) ^ (r & 7)) << 3) + (sc4 & 1) * 4;   \
            ushort2 h01, l01, h23, l23;                                        \
            hl2(pa[p].x, pa[p].y, h01, l01);                                   \
            hl2(pa[p].z, pa[p].w, h23, l23);                                   \
            ushort4 ha = {h01.x, h01.y, h23.x, h23.y};                         \
            ushort4 la = {l01.x, l01.y, l23.x, l23.y};                         \
            *(ushort4*)&Ah[BUF][ad] = ha;                                      \
            *(ushort4*)&Al[BUF][ad] = la;                                      \
        }                                                                      \
        _Pragma("unroll")                                                      \
        for (int p = 0; p < 2; ++p) {                                          \
            int r = sr + p * 16;                                               \
            int ad = r * 64 + (((sc4 >> 1) ^ (r & 7)) << 3) + (sc4 & 1) * 4;   \
            ushort2 h01, l01, h23, l23;                                        \
            hl2(pb[p].x, pb[p].y, h01, l01);                                   \
            hl2(pb[p].z, pb[p].w, h23, l23);                                   \
            ushort4 hb = {h01.x, h01.y, h23.x, h23.y};                         \
            ushort4 lb = {l01.x, l01.y, l23.x, l23.y};                         \
            *(ushort4*)&Bh[BUF][ad] = hb;                                      \
            *(ushort4*)&Bl[BUF][ad] = lb;                                      \
        }                                                                      \
    }

    f4v acc[2] = {{0.f,0.f,0.f,0.f},{0.f,0.f,0.f,0.f}};

    LOAD_CHUNK(0)
    WRITE_CHUNK(0)
    LOAD_CHUNK(1)
    __syncthreads();

    for (int kc = 0; kc < 8; ++kc) {
        const int buf = kc & 1;
#pragma unroll
        for (int ks = 0; ks < 2; ++ks) {
            const int kb = ks * 4 + lq;
            s8v afh[2], afl[2], bfh, bfl;
#pragma unroll
            for (int g = 0; g < 2; ++g) {
                int ra = mh + g * 16 + lm;
                int aa = ra * 64 + ((kb ^ (ra & 7)) << 3);
                afh[g] = *(const s8v*)&Ah[buf][aa];
                afl[g] = *(const s8v*)&Al[buf][aa];
            }
            {
                int rb = nh + lm;
                int ab = rb * 64 + ((kb ^ (rb & 7)) << 3);
                bfh = *(const s8v*)&Bh[buf][ab];
                bfl = *(const s8v*)&Bl[buf][ab];
            }
#pragma unroll
            for (int mi = 0; mi < 2; ++mi) {
                acc[mi] = __builtin_amdgcn_mfma_f32_16x16x32_bf16(
                    afh[mi], bfh, acc[mi], 0, 0, 0);
                acc[mi] = __builtin_amdgcn_mfma_f32_16x16x32_bf16(
                    afh[mi], bfl, acc[mi], 0, 0, 0);
                acc[mi] = __builtin_amdgcn_mfma_f32_16x16x32_bf16(
                    afl[mi], bfh, acc[mi], 0, 0, 0);
            }
        }
        if (kc < 7) {
            WRITE_CHUNK(buf ^ 1)
        }
        if (kc < 6) {
            LOAD_CHUNK(kc + 2)
        }
        __syncthreads();
    }

    const float CLAMP = 8192.0f;   // 2^13: scaled 8-term den < 2^104
    const float SCw   = 1.220703125e-4f;   // c = 2^-13 (pre-scale eq)
#pragma unroll
    for (int mi = 0; mi < 2; ++mi) {
#pragma unroll
        for (int p = 0; p < 4; ++p) {
            int row = i0 + mh + mi * 16 + lq * 4 + p;
            int col = j0 + nh + lm;
            float val = acc[mi][p] + (biasRow ? bias[row] : bias[col]);
            if (blockIdx.z == 0) {
                eq[(size_t)row * 512 + col] =
                    fminf(__builtin_amdgcn_exp2f(val * CS), CLAMP) * SCw;
            } else if (blockIdx.z == 1) {
                ekT[(size_t)row * 1024 + col] =
                    fminf(__builtin_amdgcn_exp2f(val * CS), CLAMP);
            } else {
                ushort2 h2 = f2bf2(val, val);
                vph[(size_t)row * 1024 + col] = h2.x;
                ushort2 l2 = f2bf2(val - bf2f(h2.x), 0.f);
                vpl[(size_t)row * 1024 + col] = l2.x;
            }
        }
    }
#undef LOAD_CHUNK
#undef WRITE_CHUNK
}

// ---------------- K2: score+softmax fused (2-way d-split, conflict-free) -----
// P[n][m] = mask ? exp2(C2 * sum_{d=0..511} Ww[d]/(1+eq*ek)) : 0 -> bf16 h/l
// Block 512 thr = 8 waves = dh(0..1, 256d half) x mg(0..3, 128 m-cols); every
// wave computes all 4 n from shared es (k-reuse 4:1; total L2 traffic
// unchanged: each (d,m) loaded once per n-block). Barrier-free engine per
// wave; dh=1 dumps acc to red[mg][comp][lane] (4B lane stride -> 0 bank
// conflicts), one barrier, dh=0 sums + fused mask/exp2/bf16/rsum epilogue.
// Grid (2,256) = 512 blocks = 16 waves/CU (2x R27). LDS 18KB.

#define TREE8(K0,K1,K2,K3,K4,K5,K6,K7,DCQ)                                     \
    {                                                                          \
        float4 wgA = *(const float4*)&wws[(DCQ)];                              \
        float4 wgB = *(const float4*)&wws[(DCQ) + 4];                          \
        _Pragma("unroll")                                                      \
        for (int nn = 0; nn < 4; ++nn) {                                       \
            float4 egA = *(const float4*)&es[nn * 512 + (DCQ)];                \
            float4 egB = *(const float4*)&es[nn * 512 + (DCQ) + 4];            \
            v2f A0 = __builtin_elementwise_fma(K0, (v2f){egA.x, egA.x}, cc2);  \
            v2f A1 = __builtin_elementwise_fma(K1, (v2f){egA.y, egA.y}, cc2);  \
            v2f A2 = __builtin_elementwise_fma(K2, (v2f){egA.z, egA.z}, cc2);  \
            v2f A3 = __builtin_elementwise_fma(K3, (v2f){egA.w, egA.w}, cc2);  \
            v2f A4 = __builtin_elementwise_fma(K4, (v2f){egB.x, egB.x}, cc2);  \
            v2f A5 = __builtin_elementwise_fma(K5, (v2f){egB.y, egB.y}, cc2);  \
            v2f A6 = __builtin_elementwise_fma(K6, (v2f){egB.z, egB.z}, cc2);  \
            v2f A7 = __builtin_elementwise_fma(K7, (v2f){egB.w, egB.w}, cc2);  \
            v2f n01 = __builtin_elementwise_fma((v2f){wgA.y, wgA.y}, A0,       \
                                                (v2f){wgA.x, wgA.x} * A1);     \
            v2f d01 = A0 * A1;                                                 \
            v2f n23 = __builtin_elementwise_fma((v2f){wgA.w, wgA.w}, A2,       \
                                                (v2f){wgA.z, wgA.z} * A3);     \
            v2f d23 = A2 * A3;                                                 \
            v2f n45 = __builtin_elementwise_fma((v2f){wgB.y, wgB.y}, A4,       \
                                                (v2f){wgB.x, wgB.x} * A5);     \
            v2f d45 = A4 * A5;                                                 \
            v2f n67 = __builtin_elementwise_fma((v2f){wgB.w, wgB.w}, A6,       \
                                                (v2f){wgB.z, wgB.z} * A7);     \
            v2f d67 = A6 * A7;                                                 \
            v2f nA = __builtin_elementwise_fma(n01, d23, n23 * d01);           \
            v2f dA = d01 * d23;                                                \
            v2f nB = __builtin_elementwise_fma(n45, d67, n67 * d45);           \
            v2f dB = d45 * d67;                                                \
            v2f num = __builtin_elementwise_fma(nA, dB, nB * dA);              \
            v2f den = dA * dB;                                                 \
            v2f r = {__builtin_amdgcn_rcpf(den.x),                             \
                     __builtin_amdgcn_rcpf(den.y)};                            \
            acc[nn] = __builtin_elementwise_fma(num, r, acc[nn]);              \
        }                                                                      \
    }

__global__ __launch_bounds__(512) void score_kernel(const float* __restrict__ eq,
                                                    const float* __restrict__ ekT,
                                                    const float* __restrict__ Ww,
                                                    const int* __restrict__ mask,
                                                    ushort* __restrict__ Ph,
                                                    ushort* __restrict__ Pl,
                                                    float* __restrict__ rsum)
{
    __shared__ __align__(16) float es[4 * 512];      // 8 KB (pre-scaled eq)
    __shared__ __align__(16) float wws[512];         // 2 KB (scaled)
    __shared__ __align__(16) float red[4 * 8 * 64];  // 8 KB [mg][comp][lane]
    const int t    = threadIdx.x;
    const int lane = t & 63;
    const int w    = t >> 6;                 // 0..7
    const int mg   = w & 3;                  // m-group (128 cols)
    const int dh   = w >> 2;                 // d-half (256 rows)
    const int mw   = blockIdx.x * 512 + mg * 128;
    const int n0   = blockIdx.y * 4;
    const int db   = dh * 256;

    const float SC = 1.220703125e-4f;        // c = 2^-13

    // stage es: 4n x 512d = 512 float4-slots; 512 threads x 1
    {
        int nl = t >> 7, c4 = t & 127;
        *(float4*)&es[nl * 512 + c4 * 4] =
            *(const float4*)&eq[(size_t)(n0 + nl) * DDIM + c4 * 4];
    }
    wws[t] = Ww[t] * SC;

    // per-lane global k stream over d-half [db, db+256)
    const float* gk = ekT + (size_t)db * MDIM + mw + lane * 2;

    v2f a0 = *(const v2f*)(gk + (size_t)0 * MDIM);
    v2f a1 = *(const v2f*)(gk + (size_t)1 * MDIM);
    v2f a2 = *(const v2f*)(gk + (size_t)2 * MDIM);
    v2f a3 = *(const v2f*)(gk + (size_t)3 * MDIM);
    v2f a4 = *(const v2f*)(gk + (size_t)4 * MDIM);
    v2f a5 = *(const v2f*)(gk + (size_t)5 * MDIM);
    v2f a6 = *(const v2f*)(gk + (size_t)6 * MDIM);
    v2f a7 = *(const v2f*)(gk + (size_t)7 * MDIM);

    __syncthreads();   // es/wws visible

    v2f acc[4] = {};
    const v2f cc2 = {1.220703125e-4f, 1.220703125e-4f};   // {c, c}

    for (int dc = 0; dc < 256; dc += 16) {
        const float* g8 = gk + (size_t)(dc + 8) * MDIM;
        v2f b0 = *(const v2f*)(g8 + (size_t)0 * MDIM);
        v2f b1 = *(const v2f*)(g8 + (size_t)1 * MDIM);
        v2f b2 = *(const v2f*)(g8 + (size_t)2 * MDIM);
        v2f b3 = *(const v2f*)(g8 + (size_t)3 * MDIM);
        v2f b4 = *(const v2f*)(g8 + (size_t)4 * MDIM);
        v2f b5 = *(const v2f*)(g8 + (size_t)5 * MDIM);
        v2f b6 = *(const v2f*)(g8 + (size_t)6 * MDIM);
        v2f b7 = *(const v2f*)(g8 + (size_t)7 * MDIM);

        TREE8(a0, a1, a2, a3, a4, a5, a6, a7, db + dc)

        if (dc + 16 < 256) {
            const float* g16 = gk + (size_t)(dc + 16) * MDIM;
            a0 = *(const v2f*)(g16 + (size_t)0 * MDIM);
            a1 = *(const v2f*)(g16 + (size_t)1 * MDIM);
            a2 = *(const v2f*)(g16 + (size_t)2 * MDIM);
            a3 = *(const v2f*)(g16 + (size_t)3 * MDIM);
            a4 = *(const v2f*)(g16 + (size_t)4 * MDIM);
            a5 = *(const v2f*)(g16 + (size_t)5 * MDIM);
            a6 = *(const v2f*)(g16 + (size_t)6 * MDIM);
            a7 = *(const v2f*)(g16 + (size_t)7 * MDIM);
        }

        TREE8(b0, b1, b2, b3, b4, b5, b6, b7, db + dc + 8)
    }

    // d-half reduction: dh=1 dumps (4B lane stride -> conflict-free)
    if (dh) {
        float* rb = &red[(mg * 8) * 64 + lane];
        rb[0 * 64] = acc[0].x; rb[1 * 64] = acc[0].y;
        rb[2 * 64] = acc[1].x; rb[3 * 64] = acc[1].y;
        rb[4 * 64] = acc[2].x; rb[5 * 64] = acc[2].y;
        rb[6 * 64] = acc[3].x; rb[7 * 64] = acc[3].y;
    }
    __syncthreads();
    if (!dh) {
        const float* rb = &red[(mg * 8) * 64 + lane];
        acc[0].x += rb[0 * 64]; acc[0].y += rb[1 * 64];
        acc[1].x += rb[2 * 64]; acc[1].y += rb[3 * 64];
        acc[2].x += rb[4 * 64]; acc[2].y += rb[5 * 64];
        acc[3].x += rb[6 * 64]; acc[3].y += rb[7 * 64];

        // fused softmax epilogue: mask + exp2 + bf16 h/l + row partials
        const float C2 = -2.8853900817779268f;   // -2*log2(e)
        const int m = mw + lane * 2;
        float rs[4];
#pragma unroll
        for (int nn = 0; nn < 4; ++nn) {
            int n = n0 + nn;
            int2 mk = *(const int2*)&mask[(size_t)n * MDIM + m];
            float p0 = mk.x ? __builtin_amdgcn_exp2f(acc[nn].x * C2) : 0.f;
            float p1 = mk.y ? __builtin_amdgcn_exp2f(acc[nn].y * C2) : 0.f;
            ushort2 h, l;
            hl2(p0, p1, h, l);
            *(ushort2*)&Ph[(size_t)n * MDIM + m] = h;
            *(ushort2*)&Pl[(size_t)n * MDIM + m] = l;
            rs[nn] = p0 + p1;
        }
#pragma unroll
        for (int off = 32; off; off >>= 1) {
            rs[0] += __shfl_xor(rs[0], off);
            rs[1] += __shfl_xor(rs[1], off);
            rs[2] += __shfl_xor(rs[2], off);
            rs[3] += __shfl_xor(rs[3], off);
        }
        if (lane == 0) {
#pragma unroll
            for (int nn = 0; nn < 4; ++nn)
                atomicAdd(&rsum[n0 + nn], rs[nn]);
        }
    }
}

// ---------------- K3: context MFMA (m-split x4 + LDS reduce) -----------------
// out[n][d] = (sum_m P[n][m]*vpT[d][m]) * rcp(rsum[n])
// grid (32,64) = 2048 blocks = 8/CU. Wave w sums m in [w*256,(w+1)*256);
// partials LDS-reduced by wave 0.
__global__ __launch_bounds__(256) void ctx_gemm(const ushort* __restrict__ Ph,
                                                const ushort* __restrict__ Pl,
                                                const ushort* __restrict__ vph,
                                                const ushort* __restrict__ vpl,
                                                const float* __restrict__ rsum,
                                                float* __restrict__ out)
{
    __shared__ __align__(16) float red[3 * 64 * 4];   // 3 KB
    const int t    = threadIdx.x;
    const int lane = t & 63;
    const int w    = t >> 6;
    const int lm   = lane & 15;
    const int lq   = lane >> 4;
    const int d0   = blockIdx.x * 16;
    const int n0   = blockIdx.y * 16;
    const int mb   = w * 256;

    const ushort* pAh = Ph  + (size_t)(n0 + lm) * MDIM + mb + lq * 8;
    const ushort* pAl = Pl  + (size_t)(n0 + lm) * MDIM + mb + lq * 8;
    const ushort* pBh = vph + (size_t)(d0 + lm) * MDIM + mb + lq * 8;
    const ushort* pBl = vpl + (size_t)(d0 + lm) * MDIM + mb + lq * 8;

    f4v acc = {0.f, 0.f, 0.f, 0.f};
#pragma unroll 4
    for (int m0 = 0; m0 < 256; m0 += 32) {
        s8v ah = *(const s8v*)(pAh + m0);
        s8v al = *(const s8v*)(pAl + m0);
        s8v bh = *(const s8v*)(pBh + m0);
        s8v bl = *(const s8v*)(pBl + m0);
        acc = __builtin_amdgcn_mfma_f32_16x16x32_bf16(ah, bh, acc, 0, 0, 0);
        acc = __builtin_amdgcn_mfma_f32_16x16x32_bf16(ah, bl, acc, 0, 0, 0);
        acc = __builtin_amdgcn_mfma_f32_16x16x32_bf16(al, bh, acc, 0, 0, 0);
    }

    if (w > 0) *(f4v*)&red[((w - 1) * 64 + lane) * 4] = acc;
    __syncthreads();
    if (w == 0) {
#pragma unroll
        for (int i = 0; i < 3; ++i)
            acc += *(const f4v*)&red[(i * 64 + lane) * 4];
#pragma unroll
        for (int p = 0; p < 4; ++p) {
            int nrow = n0 + lq * 4 + p;
            float inv = __builtin_amdgcn_rcpf(rsum[nrow]);
            out[(size_t)nrow * DDIM + d0 + lm] = acc[p] * inv;
        }
    }
}

extern "C" void kernel_launch(void* const* d_in, const int* in_sizes, int n_in,
                              void* d_out, int out_size, void* d_ws, size_t ws_size,
                              hipStream_t stream)
{
    const float* q    = (const float*)d_in[0];
    const float* k    = (const float*)d_in[1];
    const float* v    = (const float*)d_in[2];
    const int*   mask = (const int*)d_in[3];
    const float* Wq   = (const float*)d_in[4];
    const float* bq   = (const float*)d_in[5];
    const float* Wk   = (const float*)d_in[6];
    const float* bk   = (const float*)d_in[7];
    const float* Wv   = (const float*)d_in[8];
    const float* bv   = (const float*)d_in[9];
    const float* Ww   = (const float*)d_in[10];
    // d_in[11] (bw) cancels under softmax.

    float* ws    = (float*)d_ws;
    float* eq    = ws;                       // 512K floats [1024 n][512 d]
    float* ekT   = ws + 524288;              // 512K [512 d][1024 m]
    ushort* vph  = (ushort*)(ws + 1048576);  // 1M ushorts [512 d][1024 m]
    ushort* vpl  = (ushort*)(ws + 1310720);  // 1M ushorts
    ushort* Ph   = (ushort*)(ws + 1572864);  // 1M ushorts [1024 n][1024 m]
    ushort* Pl   = (ushort*)(ws + 2097152);  // 1M ushorts
    float* rsum  = ws + 2621440;             // 1K floats
    float* out   = (float*)d_out;

    const float CS = 2.8853900817779268f;    // 2*log2(e)

    proj_gemm<<<dim3(256, 1, 3), dim3(256), 0, stream>>>(q, k, v, Wq, bq, Wk, bk,
                                                         Wv, bv, eq, ekT,
                                                         vph, vpl, rsum, CS);
    score_kernel<<<dim3(2, 256), dim3(512), 0, stream>>>(eq, ekT, Ww, mask,
                                                         Ph, Pl, rsum);
    ctx_gemm<<<dim3(32, 64), dim3(256), 0, stream>>>(Ph, Pl, vph, vpl, rsum, out);
}

// Round 12
// 170.377 us; speedup vs baseline: 1.0404x; 1.0150x over previous
//
#include <hip/hip_runtime.h>
#include <hip/hip_bf16.h>
#include <float.h>

// N=1024, M=1024, D=512, fp32 in/out.
// tanh(q+k) = 1 - 2/(1+exp2(CS*(q+k))), CS=2*log2(e), exp2 factorized:
// eq[n][d]=min(exp2(CS*qp),2^13)*c (c=2^-13 pre-scaled in proj),
// ekT[d][m]=min(exp2(CS*kp),2^13)^T.
// s[n,m] = -2*sum_d Ww[d]/(1+eq*ek) (row-const dropped; softmax shift-inv).
// R19: 8-term rational merge (1 rcp per 8 d via 3-level tree, c^8 scaling).
// R20-R30 lessons: score band 54-61us across SEVEN structures; VALU floor
// ~37us; OCCUPANCY-INSENSITIVE (8/16/32 waves/CU all ~same) -> limiter is a
// per-CU throughput pipe, not latency. Second pipe identified: 10 wave-uniform
// ds_read_b128 (es/wws broadcasts) per TREE8 unit ~= 34us/CU of LDS-port time
// ~= the VALU floor -> dual-bound. All 7 structures shared this read pattern.
// R31: halve broadcast cost: 4m/lane (f4v) on R30's fused frame. Block 256thr
// = 4 waves = dh(2 x 256d) x mg(2 x 256m), all 4n from shared es; es/wws
// reads per eval HALVED (VALU conserved; k L2 traffic unchanged). Grid
// (2,256)=512 blocks = 8 waves/CU (proven sufficient). LDS 18KB. Unlike R24
// (same idea, but 4/CU convoy collapse), this keeps the barrier-free engine.
// ws: eq 2MB | ekT 2MB | vph/vpl 2MB | Ph/Pl 4MB | rsum 4KB.

#define NROWS 1024
#define DDIM  512
#define MDIM  1024

typedef __attribute__((ext_vector_type(8))) short s8v;    // 8 bf16, 4 VGPR
typedef __attribute__((ext_vector_type(4))) float f4v;
typedef __attribute__((ext_vector_type(2))) float v2f;

__device__ __forceinline__ float bf2f(ushort h) {
    return __uint_as_float(((unsigned)h) << 16);
}
__device__ __forceinline__ ushort2 f2bf2(float a, float b) {   // packed cvt
    __hip_bfloat162 t = __float22bfloat162_rn(float2{a, b});
    union { __hip_bfloat162 v; ushort2 u; } c; c.v = t;
    return c.u;
}
__device__ __forceinline__ void hl2(float a, float b, ushort2& h, ushort2& l) {
    h = f2bf2(a, b);
    l = f2bf2(a - bf2f(h.x), b - bf2f(h.y));
}

// ---------------- K1: fused projection GEMMs (64x32 tile, dbuf, 1 bar/chunk) -
// z=0: eq[n][d]:  A=q,  B=Wq, bias col, exp2+clamp, *c. Block (0,z0) zeroes rsum.
// z=1: ekT[d][m]: A=Wk, B=kk, bias row, exp2+clamp.
// z=2: vpT[d][m]: A=Wv, B=v,  bias row, bf16 h/l out.
__global__ __launch_bounds__(256) void proj_gemm(
    const float* __restrict__ q, const float* __restrict__ kk_,
    const float* __restrict__ v,
    const float* __restrict__ Wq, const float* __restrict__ bq,
    const float* __restrict__ Wk, const float* __restrict__ bk,
    const float* __restrict__ Wv, const float* __restrict__ bv,
    float* __restrict__ eq, float* __restrict__ ekT,
    ushort* __restrict__ vph, ushort* __restrict__ vpl,
    float* __restrict__ rsum, float CS)
{
    __shared__ ushort Ah[2][4096], Al[2][4096], Bh[2][2048], Bl[2][2048];

    const float* A; const float* B; const float* bias;
    int biasRow;
    if (blockIdx.z == 0)      { A = q;   B = Wq;  bias = bq; biasRow = 0; }
    else if (blockIdx.z == 1) { A = Wk;  B = kk_; bias = bk; biasRow = 1; }
    else                      { A = Wv;  B = v;   bias = bv; biasRow = 1; }

    const int bx = blockIdx.x;
    const int bi = (blockIdx.z == 0) ? (bx >> 4) : (bx >> 5);
    const int bj = (blockIdx.z == 0) ? (bx & 15) : (bx & 31);

    const int t    = threadIdx.x;
    const int lane = t & 63;
    const int w    = t >> 6;
    const int lm   = lane & 15;
    const int lq   = lane >> 4;
    const int i0   = bi * 64;
    const int j0   = bj * 32;
    const int mh   = (w >> 1) * 32;
    const int nh   = (w & 1) * 16;

    if (blockIdx.z == 0 && bx == 0) {       // zero rsum for score's atomics
        float4 zz = {0.f, 0.f, 0.f, 0.f};
        *(float4*)&rsum[t * 4] = zz;
    }

    const int sr = t >> 4, sc4 = t & 15;

    float4 pa[4], pb[2];

#define LOAD_CHUNK(KC)                                                         \
    {                                                                          \
        const int k0 = (KC) * 64;                                              \
        _Pragma("unroll")                                                      \
        for (int p = 0; p < 4; ++p)                                            \
            pa[p] = *(const float4*)&A[(size_t)(i0 + sr + p * 16) * DDIM       \
                                       + k0 + sc4 * 4];                        \
        _Pragma("unroll")                                                      \
        for (int p = 0; p < 2; ++p)                                            \
            pb[p] = *(const float4*)&B[(size_t)(j0 + sr + p * 16) * DDIM       \
                                       + k0 + sc4 * 4];                        \
    }

#define WRITE_CHUNK(BUF)                                                       \
    {                                                                          \
        _Pragma("unroll")                                                      \
        for (int p = 0; p < 4; ++p) {                                          \
            int r = sr + p * 16;                                               \
            int ad = r * 64 + (((sc4 >> 1) ^ (r & 7)) << 3) + (sc4 & 1) * 4;   \
            ushort2 h01, l01, h23, l23;                                        \
            hl2(pa[p].x, pa[p].y, h01, l01);                                   \
            hl2(pa[p].z, pa[p].w, h23, l23);                                   \
            ushort4 ha = {h01.x, h01.y, h23.x, h23.y};                         \
            ushort4 la = {l01.x, l01.y, l23.x, l23.y};                         \
            *(ushort4*)&Ah[BUF][ad] = ha;                                      \
            *(ushort4*)&Al[BUF][ad] = la;                                      \
        }                                                                      \
        _Pragma("unroll")                                                      \
        for (int p = 0; p < 2; ++p) {                                          \
            int r = sr + p * 16;                                               \
            int ad = r * 64 + (((sc4 >> 1) ^ (r & 7)) << 3) + (sc4 & 1) * 4;   \
            ushort2 h01, l01, h23, l23;                                        \
            hl2(pb[p].x, pb[p].y, h01, l01);                                   \
            hl2(pb[p].z, pb[p].w, h23, l23);                                   \
            ushort4 hb = {h01.x, h01.y, h23.x, h23.y};                         \
            ushort4 lb = {l01.x, l01.y, l23.x, l23.y};                         \
            *(ushort4*)&Bh[BUF][ad] = hb;                                      \
            *(ushort4*)&Bl[BUF][ad] = lb;                                      \
        }                                                                      \
    }

    f4v acc[2] = {{0.f,0.f,0.f,0.f},{0.f,0.f,0.f,0.f}};

    LOAD_CHUNK(0)
    WRITE_CHUNK(0)
    LOAD_CHUNK(1)
    __syncthreads();

    for (int kc = 0; kc < 8; ++kc) {
        const int buf = kc & 1;
#pragma unroll
        for (int ks = 0; ks < 2; ++ks) {
            const int kb = ks * 4 + lq;
            s8v afh[2], afl[2], bfh, bfl;
#pragma unroll
            for (int g = 0; g < 2; ++g) {
                int ra = mh + g * 16 + lm;
                int aa = ra * 64 + ((kb ^ (ra & 7)) << 3);
                afh[g] = *(const s8v*)&Ah[buf][aa];
                afl[g] = *(const s8v*)&Al[buf][aa];
            }
            {
                int rb = nh + lm;
                int ab = rb * 64 + ((kb ^ (rb & 7)) << 3);
                bfh = *(const s8v*)&Bh[buf][ab];
                bfl = *(const s8v*)&Bl[buf][ab];
            }
#pragma unroll
            for (int mi = 0; mi < 2; ++mi) {
                acc[mi] = __builtin_amdgcn_mfma_f32_16x16x32_bf16(
                    afh[mi], bfh, acc[mi], 0, 0, 0);
                acc[mi] = __builtin_amdgcn_mfma_f32_16x16x32_bf16(
                    afh[mi], bfl, acc[mi], 0, 0, 0);
                acc[mi] = __builtin_amdgcn_mfma_f32_16x16x32_bf16(
                    afl[mi], bfh, acc[mi], 0, 0, 0);
            }
        }
        if (kc < 7) {
            WRITE_CHUNK(buf ^ 1)
        }
        if (kc < 6) {
            LOAD_CHUNK(kc + 2)
        }
        __syncthreads();
    }

    const float CLAMP = 8192.0f;   // 2^13: scaled 8-term den < 2^104
    const float SCw   = 1.220703125e-4f;   // c = 2^-13 (pre-scale eq)
#pragma unroll
    for (int mi = 0; mi < 2; ++mi) {
#pragma unroll
        for (int p = 0; p < 4; ++p) {
            int row = i0 + mh + mi * 16 + lq * 4 + p;
            int col = j0 + nh + lm;
            float val = acc[mi][p] + (biasRow ? bias[row] : bias[col]);
            if (blockIdx.z == 0) {
                eq[(size_t)row * 512 + col] =
                    fminf(__builtin_amdgcn_exp2f(val * CS), CLAMP) * SCw;
            } else if (blockIdx.z == 1) {
                ekT[(size_t)row * 1024 + col] =
                    fminf(__builtin_amdgcn_exp2f(val * CS), CLAMP);
            } else {
                ushort2 h2 = f2bf2(val, val);
                vph[(size_t)row * 1024 + col] = h2.x;
                ushort2 l2 = f2bf2(val - bf2f(h2.x), 0.f);
                vpl[(size_t)row * 1024 + col] = l2.x;
            }
        }
    }
#undef LOAD_CHUNK
#undef WRITE_CHUNK
}

// ---------------- K2: score+softmax fused (4m/lane f4v, 2-way d-split) -------
// P[n][m] = mask ? exp2(C2 * sum_{d=0..511} Ww[d]/(1+eq*ek)) : 0 -> bf16 h/l
// Block 256 thr = 4 waves = dh(0..1, 256d half) x mg(0..1, 256 m-cols); lane
// owns 4 m (f4v) -> es/wws broadcast reads per eval HALVED vs R30 (the
// identified LDS-port co-bound). All 4 n from shared es (k-reuse 4:1; L2
// traffic unchanged). Barrier-free f4v engine; dh=1 dumps acc to red
// (4B lane stride, conflict-free), 1 barrier, dh=0 sums + fused epilogue.
// Grid (2,256) = 512 blocks = 8 waves/CU. LDS: es 8K + wws 2K + red 8K.

#define TREE8_F4(K0,K1,K2,K3,K4,K5,K6,K7,DCQ)                                  \
    {                                                                          \
        float4 wgA = *(const float4*)&wws[(DCQ)];                              \
        float4 wgB = *(const float4*)&wws[(DCQ) + 4];                          \
        _Pragma("unroll")                                                      \
        for (int nn = 0; nn < 4; ++nn) {                                       \
            float4 egA = *(const float4*)&es[nn * 512 + (DCQ)];                \
            float4 egB = *(const float4*)&es[nn * 512 + (DCQ) + 4];            \
            f4v A0 = __builtin_elementwise_fma(K0,                             \
                     (f4v){egA.x, egA.x, egA.x, egA.x}, cc4);                  \
            f4v A1 = __builtin_elementwise_fma(K1,                             \
                     (f4v){egA.y, egA.y, egA.y, egA.y}, cc4);                  \
            f4v A2 = __builtin_elementwise_fma(K2,                             \
                     (f4v){egA.z, egA.z, egA.z, egA.z}, cc4);                  \
            f4v A3 = __builtin_elementwise_fma(K3,                             \
                     (f4v){egA.w, egA.w, egA.w, egA.w}, cc4);                  \
            f4v A4 = __builtin_elementwise_fma(K4,                             \
                     (f4v){egB.x, egB.x, egB.x, egB.x}, cc4);                  \
            f4v A5 = __builtin_elementwise_fma(K5,                             \
                     (f4v){egB.y, egB.y, egB.y, egB.y}, cc4);                  \
            f4v A6 = __builtin_elementwise_fma(K6,                             \
                     (f4v){egB.z, egB.z, egB.z, egB.z}, cc4);                  \
            f4v A7 = __builtin_elementwise_fma(K7,                             \
                     (f4v){egB.w, egB.w, egB.w, egB.w}, cc4);                  \
            f4v n01 = __builtin_elementwise_fma(                               \
                (f4v){wgA.y, wgA.y, wgA.y, wgA.y}, A0,                         \
                (f4v){wgA.x, wgA.x, wgA.x, wgA.x} * A1);                       \
            f4v d01 = A0 * A1;                                                 \
            f4v n23 = __builtin_elementwise_fma(                               \
                (f4v){wgA.w, wgA.w, wgA.w, wgA.w}, A2,                         \
                (f4v){wgA.z, wgA.z, wgA.z, wgA.z} * A3);                       \
            f4v d23 = A2 * A3;                                                 \
            f4v n45 = __builtin_elementwise_fma(                               \
                (f4v){wgB.y, wgB.y, wgB.y, wgB.y}, A4,                         \
                (f4v){wgB.x, wgB.x, wgB.x, wgB.x} * A5);                       \
            f4v d45 = A4 * A5;                                                 \
            f4v n67 = __builtin_elementwise_fma(                               \
                (f4v){wgB.w, wgB.w, wgB.w, wgB.w}, A6,                         \
                (f4v){wgB.z, wgB.z, wgB.z, wgB.z} * A7);                       \
            f4v d67 = A6 * A7;                                                 \
            f4v nA = __builtin_elementwise_fma(n01, d23, n23 * d01);           \
            f4v dA = d01 * d23;                                                \
            f4v nB = __builtin_elementwise_fma(n45, d67, n67 * d45);           \
            f4v dB = d45 * d67;                                                \
            f4v num = __builtin_elementwise_fma(nA, dB, nB * dA);              \
            f4v den = dA * dB;                                                 \
            f4v r = {__builtin_amdgcn_rcpf(den.x),                             \
                     __builtin_amdgcn_rcpf(den.y),                             \
                     __builtin_amdgcn_rcpf(den.z),                             \
                     __builtin_amdgcn_rcpf(den.w)};                            \
            acc[nn] = __builtin_elementwise_fma(num, r, acc[nn]);              \
        }                                                                      \
    }

__global__ __launch_bounds__(256) void score_kernel(const float* __restrict__ eq,
                                                    const float* __restrict__ ekT,
                                                    const float* __restrict__ Ww,
                                                    const int* __restrict__ mask,
                                                    ushort* __restrict__ Ph,
                                                    ushort* __restrict__ Pl,
                                                    float* __restrict__ rsum)
{
    __shared__ __align__(16) float es[4 * 512];       // 8 KB (pre-scaled eq)
    __shared__ __align__(16) float wws[512];          // 2 KB (scaled)
    __shared__ __align__(16) float red[2 * 16 * 64];  // 8 KB [mg][comp][lane]
    const int t    = threadIdx.x;
    const int lane = t & 63;
    const int w    = t >> 6;                 // 0..3
    const int mg   = w & 1;                  // m-group (256 cols)
    const int dh   = w >> 1;                 // d-half (256 rows)
    const int mw   = blockIdx.x * 512 + mg * 256;
    const int n0   = blockIdx.y * 4;
    const int db   = dh * 256;

    const float SC = 1.220703125e-4f;        // c = 2^-13

    // stage es: 4n x 512d = 512 float4-slots; 256 threads x 2
#pragma unroll
    for (int p = 0; p < 2; ++p) {
        int idx = t + p * 256;
        int nl = idx >> 7, c4 = idx & 127;
        *(float4*)&es[nl * 512 + c4 * 4] =
            *(const float4*)&eq[(size_t)(n0 + nl) * DDIM + c4 * 4];
    }
    wws[t]       = Ww[t] * SC;
    wws[t + 256] = Ww[t + 256] * SC;

    // per-lane global k stream over d-half [db, db+256); lane owns 4 m
    const float* gk = ekT + (size_t)db * MDIM + mw + lane * 4;

    f4v a0 = *(const f4v*)(gk + (size_t)0 * MDIM);
    f4v a1 = *(const f4v*)(gk + (size_t)1 * MDIM);
    f4v a2 = *(const f4v*)(gk + (size_t)2 * MDIM);
    f4v a3 = *(const f4v*)(gk + (size_t)3 * MDIM);
    f4v a4 = *(const f4v*)(gk + (size_t)4 * MDIM);
    f4v a5 = *(const f4v*)(gk + (size_t)5 * MDIM);
    f4v a6 = *(const f4v*)(gk + (size_t)6 * MDIM);
    f4v a7 = *(const f4v*)(gk + (size_t)7 * MDIM);

    __syncthreads();   // es/wws visible

    f4v acc[4] = {};
    const f4v cc4 = {1.220703125e-4f, 1.220703125e-4f,
                     1.220703125e-4f, 1.220703125e-4f};   // {c,c,c,c}

    for (int dc = 0; dc < 256; dc += 16) {
        const float* g8 = gk + (size_t)(dc + 8) * MDIM;
        f4v b0 = *(const f4v*)(g8 + (size_t)0 * MDIM);
        f4v b1 = *(const f4v*)(g8 + (size_t)1 * MDIM);
        f4v b2 = *(const f4v*)(g8 + (size_t)2 * MDIM);
        f4v b3 = *(const f4v*)(g8 + (size_t)3 * MDIM);
        f4v b4 = *(const f4v*)(g8 + (size_t)4 * MDIM);
        f4v b5 = *(const f4v*)(g8 + (size_t)5 * MDIM);
        f4v b6 = *(const f4v*)(g8 + (size_t)6 * MDIM);
        f4v b7 = *(const f4v*)(g8 + (size_t)7 * MDIM);

        TREE8_F4(a0, a1, a2, a3, a4, a5, a6, a7, db + dc)

        if (dc + 16 < 256) {
            const float* g16 = gk + (size_t)(dc + 16) * MDIM;
            a0 = *(const f4v*)(g16 + (size_t)0 * MDIM);
            a1 = *(const f4v*)(g16 + (size_t)1 * MDIM);
            a2 = *(const f4v*)(g16 + (size_t)2 * MDIM);
            a3 = *(const f4v*)(g16 + (size_t)3 * MDIM);
            a4 = *(const f4v*)(g16 + (size_t)4 * MDIM);
            a5 = *(const f4v*)(g16 + (size_t)5 * MDIM);
            a6 = *(const f4v*)(g16 + (size_t)6 * MDIM);
            a7 = *(const f4v*)(g16 + (size_t)7 * MDIM);
        }

        TREE8_F4(b0, b1, b2, b3, b4, b5, b6, b7, db + dc + 8)
    }

    // d-half reduction: dh=1 dumps (4B lane stride -> conflict-free)
    if (dh) {
        float* rb = &red[(mg * 16) * 64 + lane];
#pragma unroll
        for (int nn = 0; nn < 4; ++nn) {
            rb[(nn * 4 + 0) * 64] = acc[nn].x;
            rb[(nn * 4 + 1) * 64] = acc[nn].y;
            rb[(nn * 4 + 2) * 64] = acc[nn].z;
            rb[(nn * 4 + 3) * 64] = acc[nn].w;
        }
    }
    __syncthreads();
    if (!dh) {
        const float* rb = &red[(mg * 16) * 64 + lane];
#pragma unroll
        for (int nn = 0; nn < 4; ++nn) {
            acc[nn].x += rb[(nn * 4 + 0) * 64];
            acc[nn].y += rb[(nn * 4 + 1) * 64];
            acc[nn].z += rb[(nn * 4 + 2) * 64];
            acc[nn].w += rb[(nn * 4 + 3) * 64];
        }

        // fused softmax epilogue: mask + exp2 + bf16 h/l + row partials
        const float C2 = -2.8853900817779268f;   // -2*log2(e)
        const int m = mw + lane * 4;
        float rs[4];
#pragma unroll
        for (int nn = 0; nn < 4; ++nn) {
            int n = n0 + nn;
            int4 mk = *(const int4*)&mask[(size_t)n * MDIM + m];
            float p0 = mk.x ? __builtin_amdgcn_exp2f(acc[nn].x * C2) : 0.f;
            float p1 = mk.y ? __builtin_amdgcn_exp2f(acc[nn].y * C2) : 0.f;
            float p2 = mk.z ? __builtin_amdgcn_exp2f(acc[nn].z * C2) : 0.f;
            float p3 = mk.w ? __builtin_amdgcn_exp2f(acc[nn].w * C2) : 0.f;
            ushort2 h01, l01, h23, l23;
            hl2(p0, p1, h01, l01);
            hl2(p2, p3, h23, l23);
            ushort4 hv = {h01.x, h01.y, h23.x, h23.y};
            ushort4 lv = {l01.x, l01.y, l23.x, l23.y};
            *(ushort4*)&Ph[(size_t)n * MDIM + m] = hv;
            *(ushort4*)&Pl[(size_t)n * MDIM + m] = lv;
            rs[nn] = (p0 + p1) + (p2 + p3);
        }
#pragma unroll
        for (int off = 32; off; off >>= 1) {
            rs[0] += __shfl_xor(rs[0], off);
            rs[1] += __shfl_xor(rs[1], off);
            rs[2] += __shfl_xor(rs[2], off);
            rs[3] += __shfl_xor(rs[3], off);
        }
        if (lane == 0) {
#pragma unroll
            for (int nn = 0; nn < 4; ++nn)
                atomicAdd(&rsum[n0 + nn], rs[nn]);
        }
    }
}

// ---------------- K3: context MFMA (m-split x4 + LDS reduce) -----------------
// out[n][d] = (sum_m P[n][m]*vpT[d][m]) * rcp(rsum[n])
// grid (32,64) = 2048 blocks = 8/CU. Wave w sums m in [w*256,(w+1)*256);
// partials LDS-reduced by wave 0.
__global__ __launch_bounds__(256) void ctx_gemm(const ushort* __restrict__ Ph,
                                                const ushort* __restrict__ Pl,
                                                const ushort* __restrict__ vph,
                                                const ushort* __restrict__ vpl,
                                                const float* __restrict__ rsum,
                                                float* __restrict__ out)
{
    __shared__ __align__(16) float red[3 * 64 * 4];   // 3 KB
    const int t    = threadIdx.x;
    const int lane = t & 63;
    const int w    = t >> 6;
    const int lm   = lane & 15;
    const int lq   = lane >> 4;
    const int d0   = blockIdx.x * 16;
    const int n0   = blockIdx.y * 16;
    const int mb   = w * 256;

    const ushort* pAh = Ph  + (size_t)(n0 + lm) * MDIM + mb + lq * 8;
    const ushort* pAl = Pl  + (size_t)(n0 + lm) * MDIM + mb + lq * 8;
    const ushort* pBh = vph + (size_t)(d0 + lm) * MDIM + mb + lq * 8;
    const ushort* pBl = vpl + (size_t)(d0 + lm) * MDIM + mb + lq * 8;

    f4v acc = {0.f, 0.f, 0.f, 0.f};
#pragma unroll 4
    for (int m0 = 0; m0 < 256; m0 += 32) {
        s8v ah = *(const s8v*)(pAh + m0);
        s8v al = *(const s8v*)(pAl + m0);
        s8v bh = *(const s8v*)(pBh + m0);
        s8v bl = *(const s8v*)(pBl + m0);
        acc = __builtin_amdgcn_mfma_f32_16x16x32_bf16(ah, bh, acc, 0, 0, 0);
        acc = __builtin_amdgcn_mfma_f32_16x16x32_bf16(ah, bl, acc, 0, 0, 0);
        acc = __builtin_amdgcn_mfma_f32_16x16x32_bf16(al, bh, acc, 0, 0, 0);
    }

    if (w > 0) *(f4v*)&red[((w - 1) * 64 + lane) * 4] = acc;
    __syncthreads();
    if (w == 0) {
#pragma unroll
        for (int i = 0; i < 3; ++i)
            acc += *(const f4v*)&red[(i * 64 + lane) * 4];
#pragma unroll
        for (int p = 0; p < 4; ++p) {
            int nrow = n0 + lq * 4 + p;
            float inv = __builtin_amdgcn_rcpf(rsum[nrow]);
            out[(size_t)nrow * DDIM + d0 + lm] = acc[p] * inv;
        }
    }
}

extern "C" void kernel_launch(void* const* d_in, const int* in_sizes, int n_in,
                              void* d_out, int out_size, void* d_ws, size_t ws_size,
                              hipStream_t stream)
{
    const float* q    = (const float*)d_in[0];
    const float* k    = (const float*)d_in[1];
    const float* v    = (const float*)d_in[2];
    const int*   mask = (const int*)d_in[3];
    const float* Wq   = (const float*)d_in[4];
    const float* bq   = (const float*)d_in[5];
    const float* Wk   = (const float*)d_in[6];
    const float* bk   = (const float*)d_in[7];
    const float* Wv   = (const float*)d_in[8];
    const float* bv   = (const float*)d_in[9];
    const float* Ww   = (const float*)d_in[10];
    // d_in[11] (bw) cancels under softmax.

    float* ws    = (float*)d_ws;
    float* eq    = ws;                       // 512K floats [1024 n][512 d]
    float* ekT   = ws + 524288;              // 512K [512 d][1024 m]
    ushort* vph  = (ushort*)(ws + 1048576);  // 1M ushorts [512 d][1024 m]
    ushort* vpl  = (ushort*)(ws + 1310720);  // 1M ushorts
    ushort* Ph   = (ushort*)(ws + 1572864);  // 1M ushorts [1024 n][1024 m]
    ushort* Pl   = (ushort*)(ws + 2097152);  // 1M ushorts
    float* rsum  = ws + 2621440;             // 1K floats
    float* out   = (float*)d_out;

    const float CS = 2.8853900817779268f;    // 2*log2(e)

    proj_gemm<<<dim3(256, 1, 3), dim3(256), 0, stream>>>(q, k, v, Wq, bq, Wk, bk,
                                                         Wv, bv, eq, ekT,
                                                         vph, vpl, rsum, CS);
    score_kernel<<<dim3(2, 256), dim3(256), 0, stream>>>(eq, ekT, Ww, mask,
                                                         Ph, Pl, rsum);
    ctx_gemm<<<dim3(32, 64), dim3(256), 0, stream>>>(Ph, Pl, vph, vpl, rsum, out);
}